// Round 3
// baseline (505.262 us; speedup 1.0000x reference)
//
#include <hip/hip_runtime.h>

// GAT 3-layer forward, MI355X gfx950.
// R3: layer-2 GEMM = 512-thr 256x256 ring-4 counted-vmcnt (lookahead-3, 2 waves/SIMD).

typedef __attribute__((ext_vector_type(8))) short bf16x8;
typedef __attribute__((ext_vector_type(4))) float f32x4;

#define DEVINL __device__ __forceinline__

static constexpr int NN   = 10000;
static constexpr int NE   = 160000;
static constexpr int MPAD = 10240;   // 40*256, 80*128
static constexpr int DIN  = 64;
static constexpr int CCH  = 256;
static constexpr int NH   = 8;
static constexpr int F12  = 2048;    // NH * CCH

DEVINL unsigned short f2bf(float x){
  unsigned u = __float_as_uint(x);
  u += 0x7fffu + ((u >> 16) & 1u);           // RNE
  return (unsigned short)(u >> 16);
}
DEVINL float bf2f(unsigned short h){ return __uint_as_float(((unsigned)h) << 16); }

DEVINL void gload_lds16(const unsigned short* g, unsigned short* lds){
  __builtin_amdgcn_global_load_lds(
      (__attribute__((address_space(1))) unsigned int*)(g),
      (__attribute__((address_space(3))) unsigned int*)(lds), 16, 0, 0);
}

// ---- x -> bf16
__global__ __launch_bounds__(256) void cvt_x_kernel(const float* __restrict__ x,
                                                    unsigned short* __restrict__ xbf){
  int i = blockIdx.x*256 + threadIdx.x;
  if (i >= MPAD*DIN) return;
  int r = i >> 6;
  xbf[i] = (r < NN) ? f2bf(x[i]) : (unsigned short)0;
}

// ---- W [K][Nn] f32 -> Wt [Nn][K] bf16
__global__ __launch_bounds__(256) void transpose_cvt_kernel(const float* __restrict__ W,
                                                            unsigned short* __restrict__ Wt,
                                                            int K, int Nn){
  __shared__ float tile[32][33];
  int k0 = blockIdx.x*32, n0 = blockIdx.y*32;
  int tx = threadIdx.x & 31, ty = threadIdx.x >> 5;
  #pragma unroll
  for (int r = ty; r < 32; r += 8) tile[r][tx] = W[(size_t)(k0+r)*Nn + n0 + tx];
  __syncthreads();
  #pragma unroll
  for (int r = ty; r < 32; r += 8) Wt[(size_t)(n0+r)*K + k0 + tx] = f2bf(tile[tx][r]);
}

// ---- CSR build
__global__ __launch_bounds__(256) void hist_kernel(const int* __restrict__ dst,
                                                   int* __restrict__ deg, int E_){
  int i = blockIdx.x*256 + threadIdx.x;
  if (i < E_) atomicAdd(&deg[dst[i]], 1);
}

__global__ __launch_bounds__(256) void scan_kernel(const int* __restrict__ deg,
                                                   int* __restrict__ off, int n){
  const int CH = (n + 255) / 256;
  int t = threadIdx.x;
  int lo = t*CH, hi = min(lo + CH, n);
  int s = 0;
  for (int i = lo; i < hi; i++) s += deg[i];
  __shared__ int ws[256];
  ws[t] = s;
  __syncthreads();
  for (int d = 1; d < 256; d <<= 1){
    int v = (t >= d) ? ws[t-d] : 0;
    __syncthreads();
    ws[t] += v;
    __syncthreads();
  }
  int run = ws[t] - s;
  for (int i = lo; i < hi; i++){ off[i] = run; run += deg[i]; }
  if (t == 255) off[n] = ws[255];
}

__global__ __launch_bounds__(256) void scatter_kernel(const int* __restrict__ src,
                                                      const int* __restrict__ dst,
                                                      const int* __restrict__ off,
                                                      int* __restrict__ cursor,
                                                      int* __restrict__ csrc, int E_){
  int i = blockIdx.x*256 + threadIdx.x;
  if (i >= E_) return;
  int d = dst[i];
  int pI = atomicAdd(&cursor[d], 1);
  csrc[off[d] + pI] = src[i];
}

// ---- legacy 128x128 GEMM (layers 1 and 3)
__global__ __launch_bounds__(256, 2) void gemm_bt_kernel(
    const unsigned short* __restrict__ A,
    const unsigned short* __restrict__ Bt,
    unsigned short* __restrict__ C,
    int K, int Nn)
{
  __shared__ __align__(16) unsigned short As[2][128*32];
  __shared__ __align__(16) unsigned short Bs[2][128*32];
  const int tid  = threadIdx.x;
  const int wave = tid >> 6, lane = tid & 63;
  const int wr = wave >> 1, wc = wave & 1;
  const size_t m0 = (size_t)blockIdx.x * 128;
  const size_t n0 = (size_t)blockIdx.y * 128;

  const int l4 = lane >> 2;
  const int lc = lane & 3;

  f32x4 acc[4][4];
  #pragma unroll
  for (int i = 0; i < 4; i++)
    #pragma unroll
    for (int j = 0; j < 4; j++) acc[i][j] = (f32x4){0.f,0.f,0.f,0.f};

  auto stage = [&](int buf, int kt){
    const int k0 = kt << 5;
    #pragma unroll
    for (int half = 0; half < 2; ++half){
      const int rb  = (wave + half*4) * 16;
      const int row = rb + l4;
      const int kc  = lc ^ ((row >> 1) & 3);
      gload_lds16(A + ((m0 + row)*(size_t)K + k0 + kc*8), &As[buf][rb*32]);
    }
    #pragma unroll
    for (int half = 0; half < 2; ++half){
      const int rb  = (wave + half*4) * 16;
      const int row = rb + l4;
      const int kc  = lc ^ ((row >> 1) & 3);
      gload_lds16(Bt + ((n0 + row)*(size_t)K + k0 + kc*8), &Bs[buf][rb*32]);
    }
  };

  const int nt = K >> 5;
  stage(0, 0);
  __syncthreads();

  const int rl = lane & 15;
  const int q  = lane >> 4;

  int cur = 0;
  for (int t = 0; t < nt; ++t){
    if (t + 1 < nt) stage(cur ^ 1, t + 1);
    bf16x8 af[4], bfr[4];
    #pragma unroll
    for (int m = 0; m < 4; m++){
      int row = wr*64 + m*16 + rl;
      int ch  = q ^ ((row >> 1) & 3);
      af[m] = *(const bf16x8*)&As[cur][row*32 + ch*8];
    }
    #pragma unroll
    for (int n = 0; n < 4; n++){
      int row = wc*64 + n*16 + rl;
      int ch  = q ^ ((row >> 1) & 3);
      bfr[n] = *(const bf16x8*)&Bs[cur][row*32 + ch*8];
    }
    #pragma unroll
    for (int m = 0; m < 4; m++)
      #pragma unroll
      for (int n = 0; n < 4; n++)
        acc[m][n] = __builtin_amdgcn_mfma_f32_16x16x32_bf16(af[m], bfr[n], acc[m][n], 0, 0, 0);
    __syncthreads();
    cur ^= 1;
  }

  #pragma unroll
  for (int m = 0; m < 4; m++)
    #pragma unroll
    for (int n = 0; n < 4; n++)
      #pragma unroll
      for (int r = 0; r < 4; r++){
        size_t row = m0 + wr*64 + m*16 + q*4 + r;
        size_t col = n0 + wc*64 + n*16 + rl;
        C[row*(size_t)Nn + col] = f2bf(acc[m][n][r]);
      }
}

// ---- ring-4 counted-vmcnt GEMM (layer 2): BM=256, BN=256, BK=32, 512 thr (8 waves 2Mx4N)
// per-wave 128x64 output (8x4 frags) -> 12 ds_read_b128 per 32 MFMA.
// ring-4 => lookahead-3 tiles (~1000+ cyc) covers HBM latency; vmcnt(12) steady state.
// LDS 128KB, 1 block/CU, 2 waves/SIMD.
// Swizzle: 3-bit chunk d over row-pairs (128B), d' = d ^ ((row>>1)&7); inverse applied
// to the global source so global_load_lds' linear write lands swizzled (rule #21).
__global__ __launch_bounds__(512, 2) void gemm_ring4_kernel(
    const unsigned short* __restrict__ A,
    const unsigned short* __restrict__ Bt,
    unsigned short* __restrict__ C,
    int K, int Nn)
{
  __shared__ __align__(16) unsigned short As[4][256*32];   // 4 x 16KB
  __shared__ __align__(16) unsigned short Bs[4][256*32];   // 4 x 16KB

  const int tid  = threadIdx.x;
  const int wave = tid >> 6, lane = tid & 63;
  const int wm = wave >> 2, wn = wave & 3;          // 2x4 waves, per-wave 128x64

  // XCD-bijective swizzle
  const int nwg  = gridDim.x;
  const int orig = blockIdx.x;
  const int qq = nwg >> 3, rr = nwg & 7;
  const int xcd = orig & 7, loc = orig >> 3;
  const int wg  = (xcd < rr ? xcd*(qq+1) : rr*(qq+1) + (xcd-rr)*qq) + loc;
  const int ntn = Nn >> 8;                           // N tiles of 256
  const size_t m0 = (size_t)(wg / ntn) * 256;
  const size_t n0 = (size_t)(wg % ntn) * 256;

  f32x4 acc[8][4];
  #pragma unroll
  for (int i = 0; i < 8; i++)
    #pragma unroll
    for (int j = 0; j < 4; j++) acc[i][j] = (f32x4){0.f,0.f,0.f,0.f};

  // staging lane geometry: lane l covers LDS slot (rowpair = l>>3, d' = l&7)
  // content must be global (row = rowpair*2 + (d>>2), chunk c = d&3), d = d' ^ rowpair
  const int dsw  = (lane & 7) ^ (lane >> 3);
  const int srow = (lane >> 3)*2 + (dsw >> 2);      // row within 16-row wave-load
  const int scol = (dsw & 3) * 8;                    // element offset of 16B chunk

  auto stageT = [&](int kt){
    const int r  = kt & 3;
    const int k0 = kt << 5;
    #pragma unroll
    for (int j = 0; j < 2; ++j){
      const int rb = (wave*2 + j) * 16;
      gload_lds16(A + (m0 + rb + srow)*(size_t)K + k0 + scol, &As[r][rb*32]);
    }
    #pragma unroll
    for (int j = 0; j < 2; ++j){
      const int rb = (wave*2 + j) * 16;
      gload_lds16(Bt + (n0 + rb + srow)*(size_t)K + k0 + scol, &Bs[r][rb*32]);
    }
  };

  const int nt = K >> 5;
  stageT(0);
  if (nt > 1) stageT(1);
  if (nt > 2) stageT(2);

  const int rl = lane & 15;
  const int q  = lane >> 4;
  // read-side swizzled element offsets within a 16-row frag block:
  // elem = ((rowpair_local)*64) + d'*8, rowpair_local = rl>>1 within block of 8 pairs
  const int dparts = (rl & 1) * 4;                   // d's row-parity bits
  const int rp     = rl >> 1;

  for (int kt = 0; kt < nt; ++kt){
    if (kt + 3 < nt){
      stageT(kt + 3);
      asm volatile("s_waitcnt vmcnt(12)" ::: "memory");
    } else if (kt + 2 < nt){
      asm volatile("s_waitcnt vmcnt(8)" ::: "memory");
    } else if (kt + 1 < nt){
      asm volatile("s_waitcnt vmcnt(4)" ::: "memory");
    } else {
      asm volatile("s_waitcnt vmcnt(0)" ::: "memory");
    }
    asm volatile("s_barrier" ::: "memory");

    const int r = kt & 3;
    bf16x8 af[8], bfr[4];
    #pragma unroll
    for (int m = 0; m < 8; m++){
      const int dp = ((dparts + q) ^ rp) * 8;
      af[m] = *(const bf16x8*)&As[r][(wm*64 + m*8 + rp)*64 + dp];
    }
    #pragma unroll
    for (int n = 0; n < 4; n++){
      const int dp = ((dparts + q) ^ rp) * 8;
      bfr[n] = *(const bf16x8*)&Bs[r][(wn*32 + n*8 + rp)*64 + dp];
    }
    __builtin_amdgcn_s_setprio(1);
    #pragma unroll
    for (int m = 0; m < 8; m++)
      #pragma unroll
      for (int n = 0; n < 4; n++)
        acc[m][n] = __builtin_amdgcn_mfma_f32_16x16x32_bf16(af[m], bfr[n], acc[m][n], 0, 0, 0);
    __builtin_amdgcn_s_setprio(0);
    asm volatile("s_barrier" ::: "memory");
  }

  #pragma unroll
  for (int m = 0; m < 8; m++)
    #pragma unroll
    for (int n = 0; n < 4; n++)
      #pragma unroll
      for (int r = 0; r < 4; r++){
        size_t row = m0 + wm*128 + m*16 + q*4 + r;
        size_t col = n0 + wn*64  + n*16 + rl;
        C[row*(size_t)Nn + col] = f2bf(acc[m][n][r]);
      }
}

// ---- attention logits
__global__ __launch_bounds__(256) void logits_kernel(const unsigned short* __restrict__ Hf,
                                                     const float* __restrict__ aws,
                                                     const float* __restrict__ awd,
                                                     float* __restrict__ als,
                                                     float* __restrict__ ald,
                                                     int heads){
  int gw   = (blockIdx.x*256 + threadIdx.x) >> 6;
  int lane = threadIdx.x & 63;
  int node = gw / heads;
  int head = gw - node*heads;
  if (node >= NN) return;
  const int F = heads * CCH;
  const unsigned short* hp = Hf + (size_t)node*F + head*CCH + lane*4;
  const float* wsp = aws + head*CCH + lane*4;
  const float* wdp = awd + head*CCH + lane*4;
  float s = 0.f, d = 0.f;
  #pragma unroll
  for (int j = 0; j < 4; j++){
    float hv = bf2f(hp[j]);
    s = fmaf(hv, wsp[j], s);
    d = fmaf(hv, wdp[j], d);
  }
  #pragma unroll
  for (int m = 1; m < 64; m <<= 1){ s += __shfl_xor(s, m); d += __shfl_xor(d, m); }
  if (lane == 0){ als[node*heads + head] = s; ald[node*heads + head] = d; }
}

// ---- segment softmax + aggregation + bias + ELU
template<int HH>
__global__ __launch_bounds__(256) void agg_kernel(
    const unsigned short* __restrict__ Hf,
    const int* __restrict__ off, const int* __restrict__ csrc,
    const float* __restrict__ als, const float* __restrict__ ald,
    const float* __restrict__ bias,
    unsigned short* __restrict__ actout,
    float* __restrict__ fout)
{
  constexpr int F   = HH * 256;
  constexpr int CPT = F / 256;
  const int v = blockIdx.x;
  const int t = threadIdx.x;
  const int e0 = off[v], e1 = off[v+1];
  const int deg = e1 - e0;
  __shared__ float m_sh[HH], si_sh[HH];
  __shared__ float al_sh[32][HH];
  __shared__ int   u_sh[32];

  const int hg = t >> 5;
  const int lg = t & 31;
  if (hg < HH){
    const float aldv = ald[v*HH + hg];
    float mloc = -1e30f;
    for (int i = lg; i < deg; i += 32){
      int u = csrc[e0 + i];
      float xe = als[u*HH + hg] + aldv;
      xe = xe > 0.f ? xe : 0.2f*xe;
      mloc = fmaxf(mloc, xe);
    }
    #pragma unroll
    for (int m = 1; m < 32; m <<= 1) mloc = fmaxf(mloc, __shfl_xor(mloc, m));
    float sloc = 0.f;
    for (int i = lg; i < deg; i += 32){
      int u = csrc[e0 + i];
      float xe = als[u*HH + hg] + aldv;
      xe = xe > 0.f ? xe : 0.2f*xe;
      sloc += __expf(xe - mloc);
    }
    #pragma unroll
    for (int m = 1; m < 32; m <<= 1) sloc += __shfl_xor(sloc, m);
    if (lg == 0){ m_sh[hg] = mloc; si_sh[hg] = 1.f / (sloc + 1e-16f); }
  }
  __syncthreads();

  const int head = (CPT == 8) ? hg : 0;
  const int c0   = (CPT == 8) ? ((t & 31) * 8) : t;

  float acc[CPT];
  #pragma unroll
  for (int j = 0; j < CPT; j++) acc[j] = 0.f;

  for (int base = 0; base < deg; base += 32){
    const int nch = min(deg - base, 32);
    __syncthreads();
    if (t < nch*HH){
      const int i = t / HH, h = t % HH;
      const int u = csrc[e0 + base + i];
      if (h == 0) u_sh[i] = u;
      float xe = als[u*HH + h] + ald[v*HH + h];
      xe = xe > 0.f ? xe : 0.2f*xe;
      al_sh[i][h] = __expf(xe - m_sh[h]) * si_sh[h];
    }
    __syncthreads();
    for (int i = 0; i < nch; i++){
      const float a = al_sh[i][head];
      const unsigned short* hp = Hf + (size_t)u_sh[i]*F + head*CCH + c0;
      if constexpr (CPT == 8){
        bf16x8 hv = *(const bf16x8*)hp;
        #pragma unroll
        for (int j = 0; j < 8; j++)
          acc[j] = fmaf(a, bf2f((unsigned short)hv[j]), acc[j]);
      } else {
        acc[0] = fmaf(a, bf2f(*hp), acc[0]);
      }
    }
  }

  if constexpr (CPT == 8){
    bf16x8 ov;
    #pragma unroll
    for (int j = 0; j < 8; j++){
      float o = acc[j] + bias[head*CCH + c0 + j];
      o = o > 0.f ? o : (expf(o) - 1.f);
      ov[j] = (short)f2bf(o);
    }
    *(bf16x8*)&actout[(size_t)v*F + head*CCH + c0] = ov;
  } else {
    float o = acc[0] + bias[c0];
    o = o > 0.f ? o : (expf(o) - 1.f);
    fout[(size_t)v*F + c0] = o;
  }
}

extern "C" void kernel_launch(void* const* d_in, const int* in_sizes, int n_in,
                              void* d_out, int out_size, void* d_ws, size_t ws_size,
                              hipStream_t stream)
{
  const float* x   = (const float*)d_in[0];
  const int*   ei  = (const int*)d_in[1];
  const float* W1  = (const float*)d_in[2];
  const float* as1 = (const float*)d_in[3];
  const float* ad1 = (const float*)d_in[4];
  const float* b1  = (const float*)d_in[5];
  const float* W2  = (const float*)d_in[6];
  const float* as2 = (const float*)d_in[7];
  const float* ad2 = (const float*)d_in[8];
  const float* b2  = (const float*)d_in[9];
  const float* W3  = (const float*)d_in[10];
  const float* as3 = (const float*)d_in[11];
  const float* ad3 = (const float*)d_in[12];
  const float* b3  = (const float*)d_in[13];
  float* out = (float*)d_out;
  (void)in_sizes; (void)n_in; (void)out_size; (void)ws_size;

  char* p = (char*)d_ws;
  auto carve = [&](size_t bytes)->char* {
    char* r = p; p += (bytes + 255) & ~(size_t)255; return r;
  };
  unsigned short* actA = (unsigned short*)carve((size_t)MPAD*F12*2);
  unsigned short* hbuf = (unsigned short*)carve((size_t)MPAD*F12*2);
  unsigned short* Wt1  = (unsigned short*)carve((size_t)F12*DIN*2);
  unsigned short* Wt2  = (unsigned short*)carve((size_t)F12*F12*2);
  unsigned short* Wt3  = (unsigned short*)carve((size_t)CCH*F12*2);
  float* als = (float*)carve((size_t)NN*NH*4);
  float* ald = (float*)carve((size_t)NN*NH*4);
  int* deg    = (int*)carve((size_t)NN*4);
  int* cursor = (int*)carve((size_t)NN*4);
  int* off    = (int*)carve((size_t)(NN+1)*4);
  int* csrc   = (int*)carve((size_t)NE*4);

  const int* esrc = ei;
  const int* edst = ei + NE;

  cvt_x_kernel<<<(MPAD*DIN + 255)/256, 256, 0, stream>>>(x, actA);
  transpose_cvt_kernel<<<dim3(DIN/32,  F12/32), 256, 0, stream>>>(W1, Wt1, DIN, F12);
  transpose_cvt_kernel<<<dim3(F12/32,  F12/32), 256, 0, stream>>>(W2, Wt2, F12, F12);
  transpose_cvt_kernel<<<dim3(F12/32,  CCH/32), 256, 0, stream>>>(W3, Wt3, F12, CCH);

  hipMemsetAsync(deg,    0, (size_t)NN*4, stream);
  hipMemsetAsync(cursor, 0, (size_t)NN*4, stream);
  hist_kernel<<<(NE + 255)/256, 256, 0, stream>>>(edst, deg, NE);
  scan_kernel<<<1, 256, 0, stream>>>(deg, off, NN);
  scatter_kernel<<<(NE + 255)/256, 256, 0, stream>>>(esrc, edst, off, cursor, csrc, NE);

  // layer 1: K=64 -> F12
  gemm_bt_kernel<<<dim3(MPAD/128, F12/128), 256, 0, stream>>>(actA, Wt1, hbuf, DIN, F12);
  logits_kernel<<<NN*NH/4, 256, 0, stream>>>(hbuf, as1, ad1, als, ald, NH);
  agg_kernel<8><<<NN, 256, 0, stream>>>(hbuf, off, csrc, als, ald, b1, actA, nullptr);

  // layer 2: K=2048 -> F12 (ring-4 kernel, 40x8=320 blocks of 512)
  gemm_ring4_kernel<<<(MPAD/256)*(F12/256), 512, 0, stream>>>(actA, Wt2, hbuf, F12, F12);
  logits_kernel<<<NN*NH/4, 256, 0, stream>>>(hbuf, as2, ad2, als, ald, NH);
  agg_kernel<8><<<NN, 256, 0, stream>>>(hbuf, off, csrc, als, ald, b2, actA, nullptr);

  // layer 3: K=2048 -> 256, heads=1, f32 output
  gemm_bt_kernel<<<dim3(MPAD/128, CCH/128), 256, 0, stream>>>(actA, Wt3, hbuf, F12, CCH);
  logits_kernel<<<NN/4, 256, 0, stream>>>(hbuf, as3, ad3, als, ald, 1);
  agg_kernel<1><<<NN, 256, 0, stream>>>(hbuf, off, csrc, als, ald, b3, nullptr, out);
}

// Round 4
// 465.950 us; speedup vs baseline: 1.0844x; 1.0844x over previous
//
#include <hip/hip_runtime.h>

// GAT 3-layer forward, MI355X gfx950.
// R4: layer-2 GEMM = ring-3 + 2-phase-per-K-tile schedule (counted vmcnt(6),
// per-phase barrier/lgkm/setprio), per-wave 128x64, 2 blocks/CU.

typedef __attribute__((ext_vector_type(8))) short bf16x8;
typedef __attribute__((ext_vector_type(4))) float f32x4;

#define DEVINL __device__ __forceinline__

static constexpr int NN   = 10000;
static constexpr int NE   = 160000;
static constexpr int MPAD = 10240;   // 40*256, 80*128
static constexpr int DIN  = 64;
static constexpr int CCH  = 256;
static constexpr int NH   = 8;
static constexpr int F12  = 2048;    // NH * CCH

DEVINL unsigned short f2bf(float x){
  unsigned u = __float_as_uint(x);
  u += 0x7fffu + ((u >> 16) & 1u);           // RNE
  return (unsigned short)(u >> 16);
}
DEVINL float bf2f(unsigned short h){ return __uint_as_float(((unsigned)h) << 16); }

DEVINL void gload_lds16(const unsigned short* g, unsigned short* lds){
  __builtin_amdgcn_global_load_lds(
      (__attribute__((address_space(1))) unsigned int*)(g),
      (__attribute__((address_space(3))) unsigned int*)(lds), 16, 0, 0);
}

// ---- x -> bf16
__global__ __launch_bounds__(256) void cvt_x_kernel(const float* __restrict__ x,
                                                    unsigned short* __restrict__ xbf){
  int i = blockIdx.x*256 + threadIdx.x;
  if (i >= MPAD*DIN) return;
  int r = i >> 6;
  xbf[i] = (r < NN) ? f2bf(x[i]) : (unsigned short)0;
}

// ---- W [K][Nn] f32 -> Wt [Nn][K] bf16
__global__ __launch_bounds__(256) void transpose_cvt_kernel(const float* __restrict__ W,
                                                            unsigned short* __restrict__ Wt,
                                                            int K, int Nn){
  __shared__ float tile[32][33];
  int k0 = blockIdx.x*32, n0 = blockIdx.y*32;
  int tx = threadIdx.x & 31, ty = threadIdx.x >> 5;
  #pragma unroll
  for (int r = ty; r < 32; r += 8) tile[r][tx] = W[(size_t)(k0+r)*Nn + n0 + tx];
  __syncthreads();
  #pragma unroll
  for (int r = ty; r < 32; r += 8) Wt[(size_t)(n0+r)*K + k0 + tx] = f2bf(tile[tx][r]);
}

// ---- CSR build
__global__ __launch_bounds__(256) void hist_kernel(const int* __restrict__ dst,
                                                   int* __restrict__ deg, int E_){
  int i = blockIdx.x*256 + threadIdx.x;
  if (i < E_) atomicAdd(&deg[dst[i]], 1);
}

__global__ __launch_bounds__(256) void scan_kernel(const int* __restrict__ deg,
                                                   int* __restrict__ off, int n){
  const int CH = (n + 255) / 256;
  int t = threadIdx.x;
  int lo = t*CH, hi = min(lo + CH, n);
  int s = 0;
  for (int i = lo; i < hi; i++) s += deg[i];
  __shared__ int ws[256];
  ws[t] = s;
  __syncthreads();
  for (int d = 1; d < 256; d <<= 1){
    int v = (t >= d) ? ws[t-d] : 0;
    __syncthreads();
    ws[t] += v;
    __syncthreads();
  }
  int run = ws[t] - s;
  for (int i = lo; i < hi; i++){ off[i] = run; run += deg[i]; }
  if (t == 255) off[n] = ws[255];
}

__global__ __launch_bounds__(256) void scatter_kernel(const int* __restrict__ src,
                                                      const int* __restrict__ dst,
                                                      const int* __restrict__ off,
                                                      int* __restrict__ cursor,
                                                      int* __restrict__ csrc, int E_){
  int i = blockIdx.x*256 + threadIdx.x;
  if (i >= E_) return;
  int d = dst[i];
  int pI = atomicAdd(&cursor[d], 1);
  csrc[off[d] + pI] = src[i];
}

// ---- legacy 128x128 GEMM (layers 1 and 3)
__global__ __launch_bounds__(256, 2) void gemm_bt_kernel(
    const unsigned short* __restrict__ A,
    const unsigned short* __restrict__ Bt,
    unsigned short* __restrict__ C,
    int K, int Nn)
{
  __shared__ __align__(16) unsigned short As[2][128*32];
  __shared__ __align__(16) unsigned short Bs[2][128*32];
  const int tid  = threadIdx.x;
  const int wave = tid >> 6, lane = tid & 63;
  const int wr = wave >> 1, wc = wave & 1;
  const size_t m0 = (size_t)blockIdx.x * 128;
  const size_t n0 = (size_t)blockIdx.y * 128;

  const int l4 = lane >> 2;
  const int lc = lane & 3;

  f32x4 acc[4][4];
  #pragma unroll
  for (int i = 0; i < 4; i++)
    #pragma unroll
    for (int j = 0; j < 4; j++) acc[i][j] = (f32x4){0.f,0.f,0.f,0.f};

  auto stage = [&](int buf, int kt){
    const int k0 = kt << 5;
    #pragma unroll
    for (int half = 0; half < 2; ++half){
      const int rb  = (wave + half*4) * 16;
      const int row = rb + l4;
      const int kc  = lc ^ ((row >> 1) & 3);
      gload_lds16(A + ((m0 + row)*(size_t)K + k0 + kc*8), &As[buf][rb*32]);
    }
    #pragma unroll
    for (int half = 0; half < 2; ++half){
      const int rb  = (wave + half*4) * 16;
      const int row = rb + l4;
      const int kc  = lc ^ ((row >> 1) & 3);
      gload_lds16(Bt + ((n0 + row)*(size_t)K + k0 + kc*8), &Bs[buf][rb*32]);
    }
  };

  const int nt = K >> 5;
  stage(0, 0);
  __syncthreads();

  const int rl = lane & 15;
  const int q  = lane >> 4;

  int cur = 0;
  for (int t = 0; t < nt; ++t){
    if (t + 1 < nt) stage(cur ^ 1, t + 1);
    bf16x8 af[4], bfr[4];
    #pragma unroll
    for (int m = 0; m < 4; m++){
      int row = wr*64 + m*16 + rl;
      int ch  = q ^ ((row >> 1) & 3);
      af[m] = *(const bf16x8*)&As[cur][row*32 + ch*8];
    }
    #pragma unroll
    for (int n = 0; n < 4; n++){
      int row = wc*64 + n*16 + rl;
      int ch  = q ^ ((row >> 1) & 3);
      bfr[n] = *(const bf16x8*)&Bs[cur][row*32 + ch*8];
    }
    #pragma unroll
    for (int m = 0; m < 4; m++)
      #pragma unroll
      for (int n = 0; n < 4; n++)
        acc[m][n] = __builtin_amdgcn_mfma_f32_16x16x32_bf16(af[m], bfr[n], acc[m][n], 0, 0, 0);
    __syncthreads();
    cur ^= 1;
  }

  #pragma unroll
  for (int m = 0; m < 4; m++)
    #pragma unroll
    for (int n = 0; n < 4; n++)
      #pragma unroll
      for (int r = 0; r < 4; r++){
        size_t row = m0 + wr*64 + m*16 + q*4 + r;
        size_t col = n0 + wc*64 + n*16 + rl;
        C[row*(size_t)Nn + col] = f2bf(acc[m][n][r]);
      }
}

// ---- layer-2 GEMM: ring-3 + 2-phase schedule. BM=256, BN=128, BK=32, 256 thr.
// 4 waves (2Mx2N), per-wave 128x64 (8x4 frags). LDS 72KB -> 2 blocks/CU.
// Stage lead = 2 K-tiles into slot (T+2)%3 (never the slot being read).
// vmcnt(6) once per tile (T+1's 6 issues stay in flight). Per phase:
// {ds_read subtile || 3 stage issues -> lgkmcnt(0)+sched_barrier -> setprio(1)
//  16 MFMA setprio(0) -> barrier}.
__global__ __launch_bounds__(256, 2) void gemm_l2_kernel(
    const unsigned short* __restrict__ A,
    const unsigned short* __restrict__ Bt,
    unsigned short* __restrict__ C,
    int K, int Nn)
{
  __shared__ __align__(16) unsigned short As[3][256*32];   // 3 x 16KB
  __shared__ __align__(16) unsigned short Bs[3][128*32];   // 3 x 8KB

  const int tid  = threadIdx.x;
  const int wave = tid >> 6, lane = tid & 63;
  const int wm = wave >> 1, wn = wave & 1;          // per-wave 128x64

  // XCD-bijective swizzle (n-fast within chunk)
  const int nwg  = gridDim.x;
  const int orig = blockIdx.x;
  const int qq = nwg >> 3, rr = nwg & 7;
  const int xcd = orig & 7, loc = orig >> 3;
  const int wg  = (xcd < rr ? xcd*(qq+1) : rr*(qq+1) + (xcd-rr)*qq) + loc;
  const int ntn = Nn >> 7;                           // N tiles of 128
  const size_t m0 = (size_t)(wg / ntn) * 256;
  const size_t n0 = (size_t)(wg % ntn) * 128;

  f32x4 acc[8][4];
  #pragma unroll
  for (int i = 0; i < 8; i++)
    #pragma unroll
    for (int j = 0; j < 4; j++) acc[i][j] = (f32x4){0.f,0.f,0.f,0.f};

  const int lr = lane >> 2;        // row within 16-row issue-block
  const int l3 = lane & 3;         // chunk slot

  // one staging issue: 4KB = 64 rows x 64B; wave w covers rows base+w*16+lr
  auto stageA = [&](int slot, int k0, int j){
    const int row = j*64 + wave*16 + lr;
    const int kc  = l3 ^ ((row >> 1) & 3);
    gload_lds16(A + (m0 + row)*(size_t)K + k0 + kc*8, &As[slot][(j*64 + wave*16)*32]);
  };
  auto stageB = [&](int slot, int k0, int j){
    const int row = j*64 + wave*16 + lr;
    const int kc  = l3 ^ ((row >> 1) & 3);
    gload_lds16(Bt + (n0 + row)*(size_t)K + k0 + kc*8, &Bs[slot][(j*64 + wave*16)*32]);
  };
  auto stageTile = [&](int T){
    const int slot = T % 3, k0 = T << 5;
    #pragma unroll
    for (int j = 0; j < 4; j++) stageA(slot, k0, j);
    #pragma unroll
    for (int j = 0; j < 2; j++) stageB(slot, k0, j);
  };

  const int nt = K >> 5;
  stageTile(0);
  if (nt > 1) stageTile(1);

  const int rl = lane & 15;
  const int q  = lane >> 4;

  for (int T = 0; T < nt; ++T){
    if (T + 1 < nt) asm volatile("s_waitcnt vmcnt(6)" ::: "memory");
    else            asm volatile("s_waitcnt vmcnt(0)" ::: "memory");
    __builtin_amdgcn_s_barrier();

    const int slot = T % 3;
    const bool st  = (T + 2 < nt);
    const int s2   = (T + 2) % 3;
    const int k2   = (T + 2) << 5;

    bf16x8 af[8], bfr[4];
    // ---- phase 0: read m-frags 0-3 + all B frags; stage 3 issues; MFMA m0-3
    #pragma unroll
    for (int m = 0; m < 4; m++){
      const int row = wm*128 + m*16 + rl;
      const int ch  = q ^ ((row >> 1) & 3);
      af[m] = *(const bf16x8*)&As[slot][row*32 + ch*8];
    }
    #pragma unroll
    for (int n = 0; n < 4; n++){
      const int row = wn*64 + n*16 + rl;
      const int ch  = q ^ ((row >> 1) & 3);
      bfr[n] = *(const bf16x8*)&Bs[slot][row*32 + ch*8];
    }
    if (st){ stageA(s2, k2, 0); stageA(s2, k2, 1); stageA(s2, k2, 2); }
    asm volatile("s_waitcnt lgkmcnt(0)" ::: "memory");
    __builtin_amdgcn_sched_barrier(0);
    __builtin_amdgcn_s_setprio(1);
    #pragma unroll
    for (int m = 0; m < 4; m++)
      #pragma unroll
      for (int n = 0; n < 4; n++)
        acc[m][n] = __builtin_amdgcn_mfma_f32_16x16x32_bf16(af[m], bfr[n], acc[m][n], 0, 0, 0);
    __builtin_amdgcn_s_setprio(0);
    __builtin_amdgcn_s_barrier();

    // ---- phase 1: read m-frags 4-7; stage 3 issues; MFMA m4-7
    #pragma unroll
    for (int m = 4; m < 8; m++){
      const int row = wm*128 + m*16 + rl;
      const int ch  = q ^ ((row >> 1) & 3);
      af[m] = *(const bf16x8*)&As[slot][row*32 + ch*8];
    }
    if (st){ stageA(s2, k2, 3); stageB(s2, k2, 0); stageB(s2, k2, 1); }
    asm volatile("s_waitcnt lgkmcnt(0)" ::: "memory");
    __builtin_amdgcn_sched_barrier(0);
    __builtin_amdgcn_s_setprio(1);
    #pragma unroll
    for (int m = 4; m < 8; m++)
      #pragma unroll
      for (int n = 0; n < 4; n++)
        acc[m][n] = __builtin_amdgcn_mfma_f32_16x16x32_bf16(af[m], bfr[n], acc[m][n], 0, 0, 0);
    __builtin_amdgcn_s_setprio(0);
    __builtin_amdgcn_s_barrier();
  }

  #pragma unroll
  for (int m = 0; m < 8; m++)
    #pragma unroll
    for (int n = 0; n < 4; n++)
      #pragma unroll
      for (int r = 0; r < 4; r++){
        size_t row = m0 + wm*128 + m*16 + q*4 + r;
        size_t col = n0 + wn*64  + n*16 + rl;
        C[row*(size_t)Nn + col] = f2bf(acc[m][n][r]);
      }
}

// ---- attention logits
__global__ __launch_bounds__(256) void logits_kernel(const unsigned short* __restrict__ Hf,
                                                     const float* __restrict__ aws,
                                                     const float* __restrict__ awd,
                                                     float* __restrict__ als,
                                                     float* __restrict__ ald,
                                                     int heads){
  int gw   = (blockIdx.x*256 + threadIdx.x) >> 6;
  int lane = threadIdx.x & 63;
  int node = gw / heads;
  int head = gw - node*heads;
  if (node >= NN) return;
  const int F = heads * CCH;
  const unsigned short* hp = Hf + (size_t)node*F + head*CCH + lane*4;
  const float* wsp = aws + head*CCH + lane*4;
  const float* wdp = awd + head*CCH + lane*4;
  float s = 0.f, d = 0.f;
  #pragma unroll
  for (int j = 0; j < 4; j++){
    float hv = bf2f(hp[j]);
    s = fmaf(hv, wsp[j], s);
    d = fmaf(hv, wdp[j], d);
  }
  #pragma unroll
  for (int m = 1; m < 64; m <<= 1){ s += __shfl_xor(s, m); d += __shfl_xor(d, m); }
  if (lane == 0){ als[node*heads + head] = s; ald[node*heads + head] = d; }
}

// ---- segment softmax + aggregation + bias + ELU
template<int HH>
__global__ __launch_bounds__(256) void agg_kernel(
    const unsigned short* __restrict__ Hf,
    const int* __restrict__ off, const int* __restrict__ csrc,
    const float* __restrict__ als, const float* __restrict__ ald,
    const float* __restrict__ bias,
    unsigned short* __restrict__ actout,
    float* __restrict__ fout)
{
  constexpr int F   = HH * 256;
  constexpr int CPT = F / 256;
  const int v = blockIdx.x;
  const int t = threadIdx.x;
  const int e0 = off[v], e1 = off[v+1];
  const int deg = e1 - e0;
  __shared__ float m_sh[HH], si_sh[HH];
  __shared__ float al_sh[32][HH];
  __shared__ int   u_sh[32];

  const int hg = t >> 5;
  const int lg = t & 31;
  if (hg < HH){
    const float aldv = ald[v*HH + hg];
    float mloc = -1e30f;
    for (int i = lg; i < deg; i += 32){
      int u = csrc[e0 + i];
      float xe = als[u*HH + hg] + aldv;
      xe = xe > 0.f ? xe : 0.2f*xe;
      mloc = fmaxf(mloc, xe);
    }
    #pragma unroll
    for (int m = 1; m < 32; m <<= 1) mloc = fmaxf(mloc, __shfl_xor(mloc, m));
    float sloc = 0.f;
    for (int i = lg; i < deg; i += 32){
      int u = csrc[e0 + i];
      float xe = als[u*HH + hg] + aldv;
      xe = xe > 0.f ? xe : 0.2f*xe;
      sloc += __expf(xe - mloc);
    }
    #pragma unroll
    for (int m = 1; m < 32; m <<= 1) sloc += __shfl_xor(sloc, m);
    if (lg == 0){ m_sh[hg] = mloc; si_sh[hg] = 1.f / (sloc + 1e-16f); }
  }
  __syncthreads();

  const int head = (CPT == 8) ? hg : 0;
  const int c0   = (CPT == 8) ? ((t & 31) * 8) : t;

  float acc[CPT];
  #pragma unroll
  for (int j = 0; j < CPT; j++) acc[j] = 0.f;

  for (int base = 0; base < deg; base += 32){
    const int nch = min(deg - base, 32);
    __syncthreads();
    if (t < nch*HH){
      const int i = t / HH, h = t % HH;
      const int u = csrc[e0 + base + i];
      if (h == 0) u_sh[i] = u;
      float xe = als[u*HH + h] + ald[v*HH + h];
      xe = xe > 0.f ? xe : 0.2f*xe;
      al_sh[i][h] = __expf(xe - m_sh[h]) * si_sh[h];
    }
    __syncthreads();
    for (int i = 0; i < nch; i++){
      const float a = al_sh[i][head];
      const unsigned short* hp = Hf + (size_t)u_sh[i]*F + head*CCH + c0;
      if constexpr (CPT == 8){
        bf16x8 hv = *(const bf16x8*)hp;
        #pragma unroll
        for (int j = 0; j < 8; j++)
          acc[j] = fmaf(a, bf2f((unsigned short)hv[j]), acc[j]);
      } else {
        acc[0] = fmaf(a, bf2f(*hp), acc[0]);
      }
    }
  }

  if constexpr (CPT == 8){
    bf16x8 ov;
    #pragma unroll
    for (int j = 0; j < 8; j++){
      float o = acc[j] + bias[head*CCH + c0 + j];
      o = o > 0.f ? o : (expf(o) - 1.f);
      ov[j] = (short)f2bf(o);
    }
    *(bf16x8*)&actout[(size_t)v*F + head*CCH + c0] = ov;
  } else {
    float o = acc[0] + bias[c0];
    o = o > 0.f ? o : (expf(o) - 1.f);
    fout[(size_t)v*F + c0] = o;
  }
}

extern "C" void kernel_launch(void* const* d_in, const int* in_sizes, int n_in,
                              void* d_out, int out_size, void* d_ws, size_t ws_size,
                              hipStream_t stream)
{
  const float* x   = (const float*)d_in[0];
  const int*   ei  = (const int*)d_in[1];
  const float* W1  = (const float*)d_in[2];
  const float* as1 = (const float*)d_in[3];
  const float* ad1 = (const float*)d_in[4];
  const float* b1  = (const float*)d_in[5];
  const float* W2  = (const float*)d_in[6];
  const float* as2 = (const float*)d_in[7];
  const float* ad2 = (const float*)d_in[8];
  const float* b2  = (const float*)d_in[9];
  const float* W3  = (const float*)d_in[10];
  const float* as3 = (const float*)d_in[11];
  const float* ad3 = (const float*)d_in[12];
  const float* b3  = (const float*)d_in[13];
  float* out = (float*)d_out;
  (void)in_sizes; (void)n_in; (void)out_size; (void)ws_size;

  char* p = (char*)d_ws;
  auto carve = [&](size_t bytes)->char* {
    char* r = p; p += (bytes + 255) & ~(size_t)255; return r;
  };
  unsigned short* actA = (unsigned short*)carve((size_t)MPAD*F12*2);
  unsigned short* hbuf = (unsigned short*)carve((size_t)MPAD*F12*2);
  unsigned short* Wt1  = (unsigned short*)carve((size_t)F12*DIN*2);
  unsigned short* Wt2  = (unsigned short*)carve((size_t)F12*F12*2);
  unsigned short* Wt3  = (unsigned short*)carve((size_t)CCH*F12*2);
  float* als = (float*)carve((size_t)NN*NH*4);
  float* ald = (float*)carve((size_t)NN*NH*4);
  int* deg    = (int*)carve((size_t)NN*4);
  int* cursor = (int*)carve((size_t)NN*4);
  int* off    = (int*)carve((size_t)(NN+1)*4);
  int* csrc   = (int*)carve((size_t)NE*4);

  const int* esrc = ei;
  const int* edst = ei + NE;

  cvt_x_kernel<<<(MPAD*DIN + 255)/256, 256, 0, stream>>>(x, actA);
  transpose_cvt_kernel<<<dim3(DIN/32,  F12/32), 256, 0, stream>>>(W1, Wt1, DIN, F12);
  transpose_cvt_kernel<<<dim3(F12/32,  F12/32), 256, 0, stream>>>(W2, Wt2, F12, F12);
  transpose_cvt_kernel<<<dim3(F12/32,  CCH/32), 256, 0, stream>>>(W3, Wt3, F12, CCH);

  hipMemsetAsync(deg,    0, (size_t)NN*4, stream);
  hipMemsetAsync(cursor, 0, (size_t)NN*4, stream);
  hist_kernel<<<(NE + 255)/256, 256, 0, stream>>>(edst, deg, NE);
  scan_kernel<<<1, 256, 0, stream>>>(deg, off, NN);
  scatter_kernel<<<(NE + 255)/256, 256, 0, stream>>>(esrc, edst, off, cursor, csrc, NE);

  // layer 1: K=64 -> F12
  gemm_bt_kernel<<<dim3(MPAD/128, F12/128), 256, 0, stream>>>(actA, Wt1, hbuf, DIN, F12);
  logits_kernel<<<NN*NH/4, 256, 0, stream>>>(hbuf, as1, ad1, als, ald, NH);
  agg_kernel<8><<<NN, 256, 0, stream>>>(hbuf, off, csrc, als, ald, b1, actA, nullptr);

  // layer 2: K=2048 -> F12 (ring-3 2-phase kernel, 40x16=640 blocks)
  gemm_l2_kernel<<<(MPAD/256)*(F12/128), 256, 0, stream>>>(actA, Wt2, hbuf, F12, F12);
  logits_kernel<<<NN*NH/4, 256, 0, stream>>>(hbuf, as2, ad2, als, ald, NH);
  agg_kernel<8><<<NN, 256, 0, stream>>>(hbuf, off, csrc, als, ald, b2, actA, nullptr);

  // layer 3: K=2048 -> 256, heads=1, f32 output
  gemm_bt_kernel<<<dim3(MPAD/128, CCH/128), 256, 0, stream>>>(actA, Wt3, hbuf, F12, CCH);
  logits_kernel<<<NN/4, 256, 0, stream>>>(hbuf, as3, ad3, als, ald, 1);
  agg_kernel<1><<<NN, 256, 0, stream>>>(hbuf, off, csrc, als, ald, b3, nullptr, out);
}